// Round 3
// baseline (1018.467 us; speedup 1.0000x reference)
//
#include <hip/hip_runtime.h>
#include <math.h>

#define NB 256       // batch
#define HT 17
#define WT 17
#define HI 384
#define WI 384
#define LH 368
#define LW 368
#define NTEMPL 289   // HT*WT
#define TPAD 20      // padded template row width (float4-friendly)
#define TY 32        // output tile rows per block
#define TX 128       // output tile cols per block
#define NTXT 3       // x tiles (3*128 = 384)
#define NTYT 12      // y tiles (12*32 = 384)
#define NTILES 36    // tiles per batch
#define BR 48        // bg tile rows (TY + 16)
#define BP 144       // bg pitch = TX + 16 (multiple of 4)
#define TEMP_INV 25.0f
#define EPSV 1e-6f

// ---------------- kernel 1: per-batch template normalization ----------------
__global__ __launch_bounds__(256) void tmpl_norm_kernel(
    const float* __restrict__ piece, float* __restrict__ tn) {
    int b = blockIdx.x;
    const float* x = piece + b * NTEMPL;
    int tid = threadIdx.x;
    int wid = tid >> 6, lane = tid & 63;

    float v0 = (tid < NTEMPL) ? x[tid] : 0.f;
    float v1 = (tid + 256 < NTEMPL) ? x[tid + 256] : 0.f;

    __shared__ float sred[4];
    float s = v0 + v1;
    #pragma unroll
    for (int o = 32; o > 0; o >>= 1) s += __shfl_down(s, o, 64);
    if (lane == 0) sred[wid] = s;
    __syncthreads();
    float mean = (sred[0] + sred[1] + sred[2] + sred[3]) * (1.0f / NTEMPL);

    float d0 = (tid < NTEMPL) ? (v0 - mean) : 0.f;
    float d1 = (tid + 256 < NTEMPL) ? (v1 - mean) : 0.f;
    float q = d0 * d0 + d1 * d1;
    __syncthreads();
    #pragma unroll
    for (int o = 32; o > 0; o >>= 1) q += __shfl_down(q, o, 64);
    if (lane == 0) sred[wid] = q;
    __syncthreads();
    float var = (sred[0] + sred[1] + sred[2] + sred[3]) * (1.0f / (NTEMPL - 1));
    float stdv = sqrtf(var);
    if (stdv < EPSV) stdv = EPSV;
    float inv = 1.0f / stdv;

    float* o = tn + b * (HT * TPAD);
    for (int sIdx = tid; sIdx < HT * TPAD; sIdx += 256) {
        int i = sIdx / TPAD, j = sIdx % TPAD;
        o[sIdx] = (j < WT) ? (x[i * WT + j] - mean) * inv : 0.f;
    }
}

// ---------------- main-loop step: compile-time slot rotation ----------------
// At step i, bbf slots hold bg rows ty4+i .. ty4+i+3 (slot = row & 3).
// Template row i+1 is software-pipelined into ttf[(C+1)&1] (global, L1-broadcast).
template<int C, bool LAST>
__device__ __forceinline__ void corr_step(
    int ib, int ty4, int xb,
    const float* __restrict__ tp,
    const float (*__restrict__ bg)[BP],
    float (&bbf)[4][TPAD], float (&ttf)[2][TPAD], float (&acc)[4][4])
{
    const int i = ib + C;
    if (!LAST) {
        const float4* tq = (const float4*)(tp + (i + 1) * TPAD);
        #pragma unroll
        for (int q = 0; q < 5; ++q) ((float4*)ttf[(C + 1) & 1])[q] = tq[q];
    }
    {   // load new bg row (ty4+i+3) into slot (C+3)&3 — consumed late (ry=3)
        const float4* br = (const float4*)&bg[ty4 + i + 3][xb];
        #pragma unroll
        for (int q = 0; q < 5; ++q) ((float4*)bbf[(C + 3) & 3])[q] = br[q];
    }
    const float* tc = ttf[C & 1];
    #pragma unroll
    for (int ry = 0; ry < 4; ++ry) {
        const float* rw = bbf[(C + ry) & 3];
        #pragma unroll
        for (int j = 0; j < 17; ++j) {
            const float tv = tc[j];
            #pragma unroll
            for (int k = 0; k < 4; ++k)
                acc[ry][k] = fmaf(tv, rw[j + k], acc[ry][k]);
        }
    }
}

// ---------------- kernel 2: correlation + per-tile softmax partials ----------------
// LDS = bg only (27.7 KB) -> 4 blocks/CU (vs 2 with c1/c2 arrays). Window
// stats are computed per-thread from bg re-reads (+~1100 VALU) — trades VALU
// for 2x occupancy.
__global__ __launch_bounds__(256, 4) void corr_kernel(
    const float* __restrict__ bgg, const float* __restrict__ tn,
    float* __restrict__ partials) {
    int blk = blockIdx.x;
    int b = blk / NTILES;
    int t = blk % NTILES;
    int ty0 = (t / NTXT) * TY;
    int tx0 = (t % NTXT) * TX;
    const float* img = bgg + (size_t)b * HI * WI;
    const float* tp  = tn + b * (HT * TPAD);

    __shared__ float bg[BR][BP];   // 27648 B
    __shared__ float redm[4], redl[4], redy[4], redx[4];

    int tid = threadIdx.x;
    int wid = tid >> 6, lane = tid & 63;

    // ---- stage bg tile (zero-filled OOB); rows/cols are 4-aligned vs 384 ----
    for (int l = tid; l < BR * (BP / 4); l += 256) {
        int r = l / (BP / 4), c = (l % (BP / 4)) * 4;
        int iy = ty0 + r, ix = tx0 + c;
        float4 v = make_float4(0.f, 0.f, 0.f, 0.f);
        if (iy < HI && ix < WI) v = *(const float4*)(img + iy * WI + ix);
        *(float4*)&bg[r][c] = v;
    }
    __syncthreads();

    // ---- main loop: 4x4 micro-tile, rolling 4-row register window ----
    int ty4 = (tid >> 5) * 4;    // 0..28
    int xb  = (tid & 31) * 4;    // 0..124
    float bbf[4][TPAD];
    float ttf[2][TPAD];
    float acc[4][4] = {};

    #pragma unroll
    for (int m = 0; m < 3; ++m) {
        const float4* br = (const float4*)&bg[ty4 + m][xb];
        #pragma unroll
        for (int q = 0; q < 5; ++q) ((float4*)bbf[m])[q] = br[q];
    }
    {
        const float4* t0 = (const float4*)tp;
        #pragma unroll
        for (int q = 0; q < 5; ++q) ((float4*)ttf[0])[q] = t0[q];
    }

    for (int ib = 0; ib < 16; ib += 4) {
        corr_step<0, false>(ib, ty4, xb, tp, bg, bbf, ttf, acc);
        corr_step<1, false>(ib, ty4, xb, tp, bg, bbf, ttf, acc);
        corr_step<2, false>(ib, ty4, xb, tp, bg, bbf, ttf, acc);
        corr_step<3, false>(ib, ty4, xb, tp, bg, bbf, ttf, acc);
    }
    corr_step<0, true>(16, ty4, xb, tp, bg, bbf, ttf, acc);

    // ---- per-thread window stats: 20-column running sums in registers ----
    // (no barrier needed: everyone only READS bg from here)
    float cs[TPAD], cs2[TPAD];
    {   // rows ty4 .. ty4+16
        const float4* r0 = (const float4*)&bg[ty4][xb];
        float tmp[TPAD];
        #pragma unroll
        for (int q = 0; q < 5; ++q) ((float4*)tmp)[q] = r0[q];
        #pragma unroll
        for (int j = 0; j < TPAD; ++j) { float v = tmp[j]; cs[j] = v; cs2[j] = v * v; }
    }
    #pragma unroll
    for (int r = 1; r < HT; ++r) {
        const float4* rr = (const float4*)&bg[ty4 + r][xb];
        float tmp[TPAD];
        #pragma unroll
        for (int q = 0; q < 5; ++q) ((float4*)tmp)[q] = rr[q];
        #pragma unroll
        for (int j = 0; j < TPAD; ++j) { float v = tmp[j]; cs[j] += v; cs2[j] = fmaf(v, v, cs2[j]); }
    }

    const float invn = 1.0f / NTEMPL;
    float corr[4][4];
    float m = -INFINITY;
    #pragma unroll
    for (int ry = 0; ry < 4; ++ry) {
        // cs/cs2 currently hold column sums over rows [ty4+ry, ty4+ry+16]
        float s1 = 0.f, s2 = 0.f;
        #pragma unroll
        for (int j = 0; j < HT; ++j) { s1 += cs[j]; s2 += cs2[j]; }
        int oy = ty0 + ty4 + ry;
        #pragma unroll
        for (int k = 0; k < 4; ++k) {
            float mu = s1 * invn;
            float var = s2 * invn - mu * mu;
            if (var < EPSV) var = EPSV;
            float cv = acc[ry][k] / sqrtf(var);
            int ox = tx0 + xb + k;
            if (oy < LH && ox < LW) m = fmaxf(m, cv);
            else cv = -INFINITY;
            corr[ry][k] = cv;
            if (k < 3) {
                s1 += cs[k + HT] - cs[k];
                s2 += cs2[k + HT] - cs2[k];
            }
        }
        if (ry < 3) {   // roll window down one row: add row ty4+ry+17, drop row ty4+ry
            float tn2[TPAD], to2[TPAD];
            const float4* rn = (const float4*)&bg[ty4 + ry + HT][xb];
            const float4* ro = (const float4*)&bg[ty4 + ry][xb];
            #pragma unroll
            for (int q = 0; q < 5; ++q) { ((float4*)tn2)[q] = rn[q]; ((float4*)to2)[q] = ro[q]; }
            #pragma unroll
            for (int j = 0; j < TPAD; ++j) {
                float vn = tn2[j], vo = to2[j];
                cs[j] += vn - vo;
                cs2[j] = fmaf(vn, vn, cs2[j]);
                cs2[j] = fmaf(-vo, vo, cs2[j]);
            }
        }
    }

    // ---- block max ----
    float mm = m;
    #pragma unroll
    for (int o = 32; o > 0; o >>= 1) mm = fmaxf(mm, __shfl_down(mm, o, 64));
    if (lane == 0) redm[wid] = mm;
    __syncthreads();
    float M = fmaxf(fmaxf(redm[0], redm[1]), fmaxf(redm[2], redm[3]));

    // ---- partial softmax sums relative to tile max ----
    float l = 0.f, sy = 0.f, sx = 0.f;
    #pragma unroll
    for (int ry = 0; ry < 4; ++ry) {
        int oy = ty0 + ty4 + ry;
        #pragma unroll
        for (int k = 0; k < 4; ++k) {
            float cv = corr[ry][k];
            float e = (cv == -INFINITY) ? 0.f : __expf((cv - M) * TEMP_INV);
            l += e;
            sy = fmaf(e, (float)oy, sy);
            sx = fmaf(e, (float)(tx0 + xb + k), sx);
        }
    }
    #pragma unroll
    for (int o = 32; o > 0; o >>= 1) {
        l  += __shfl_down(l, o, 64);
        sy += __shfl_down(sy, o, 64);
        sx += __shfl_down(sx, o, 64);
    }
    if (lane == 0) { redl[wid] = l; redy[wid] = sy; redx[wid] = sx; }
    __syncthreads();
    if (tid == 0) {
        float* p = partials + (size_t)blk * 4;
        p[0] = M;
        p[1] = redl[0] + redl[1] + redl[2] + redl[3];
        p[2] = redy[0] + redy[1] + redy[2] + redy[3];
        p[3] = redx[0] + redx[1] + redx[2] + redx[3];
    }
}

// ---------------- kernel 3: per-batch merge of tile partials ----------------
__global__ __launch_bounds__(256) void reduce_kernel(
    const float* __restrict__ partials, float* __restrict__ out) {
    int b = blockIdx.x;
    int tid = threadIdx.x;
    int wid = tid >> 6, lane = tid & 63;

    float m = -INFINITY, l = 0.f, sy = 0.f, sx = 0.f;
    if (tid < NTILES) {
        const float* p = partials + (size_t)(b * NTILES + tid) * 4;
        m = p[0]; l = p[1]; sy = p[2]; sx = p[3];
    }
    __shared__ float rm[4], rl[4], ry[4], rx[4];
    float mm = m;
    #pragma unroll
    for (int o = 32; o > 0; o >>= 1) mm = fmaxf(mm, __shfl_down(mm, o, 64));
    if (lane == 0) rm[wid] = mm;
    __syncthreads();
    float M = fmaxf(fmaxf(rm[0], rm[1]), fmaxf(rm[2], rm[3]));

    float sc = (m == -INFINITY) ? 0.f : __expf((m - M) * TEMP_INV);
    l *= sc; sy *= sc; sx *= sc;
    #pragma unroll
    for (int o = 32; o > 0; o >>= 1) {
        l  += __shfl_down(l, o, 64);
        sy += __shfl_down(sy, o, 64);
        sx += __shfl_down(sx, o, 64);
    }
    if (lane == 0) { rl[wid] = l; ry[wid] = sy; rx[wid] = sx; }
    __syncthreads();
    if (tid == 0) {
        float L  = rl[0] + rl[1] + rl[2] + rl[3];
        float SY = ry[0] + ry[1] + ry[2] + ry[3];
        float SX = rx[0] + rx[1] + rx[2] + rx[3];
        out[b * 2 + 0] = SX / L - 183.5f;
        out[b * 2 + 1] = SY / L - 183.5f;
        out[2 * NB + b] = M;
    }
}

extern "C" void kernel_launch(void* const* d_in, const int* in_sizes, int n_in,
                              void* d_out, int out_size, void* d_ws, size_t ws_size,
                              hipStream_t stream) {
    const float* piece = (const float*)d_in[0];   // [256,1,17,17]
    const float* bgg   = (const float*)d_in[1];   // [256,1,384,384]
    float* out = (float*)d_out;                   // 512 offsets + 256 max_corr

    float* tn = (float*)d_ws;                     // 256 * 340 floats
    float* partials = tn + NB * HT * TPAD;        // 256*36*4 floats

    tmpl_norm_kernel<<<NB, 256, 0, stream>>>(piece, tn);
    corr_kernel<<<NB * NTILES, 256, 0, stream>>>(bgg, tn, partials);
    reduce_kernel<<<NB, 256, 0, stream>>>(partials, out);
}

// Round 4
// 566.567 us; speedup vs baseline: 1.7976x; 1.7976x over previous
//
#include <hip/hip_runtime.h>
#include <math.h>

#define NB 256       // batch
#define HT 17
#define WT 17
#define HI 384
#define WI 384
#define LH 368
#define LW 368
#define NTEMPL 289   // HT*WT
#define TPAD 20      // padded template row width (float4-friendly)
#define TY 32        // output tile rows per block
#define TX 128       // output tile cols per block
#define NTXT 3       // x tiles (3*128 = 384)
#define NTYT 12      // y tiles (12*32 = 384)
#define NTILES 36    // tiles per batch
#define BR 48        // bg tile rows (TY + 16)
#define BP 144       // bg pitch = TX + 16 (multiple of 4)
#define TEMP_INV 25.0f
#define EPSV 1e-6f

// ---------------- kernel 1: per-batch template normalization ----------------
__global__ __launch_bounds__(256) void tmpl_norm_kernel(
    const float* __restrict__ piece, float* __restrict__ tn) {
    int b = blockIdx.x;
    const float* x = piece + b * NTEMPL;
    int tid = threadIdx.x;
    int wid = tid >> 6, lane = tid & 63;

    float v0 = (tid < NTEMPL) ? x[tid] : 0.f;
    float v1 = (tid + 256 < NTEMPL) ? x[tid + 256] : 0.f;

    __shared__ float sred[4];
    float s = v0 + v1;
    #pragma unroll
    for (int o = 32; o > 0; o >>= 1) s += __shfl_down(s, o, 64);
    if (lane == 0) sred[wid] = s;
    __syncthreads();
    float mean = (sred[0] + sred[1] + sred[2] + sred[3]) * (1.0f / NTEMPL);

    float d0 = (tid < NTEMPL) ? (v0 - mean) : 0.f;
    float d1 = (tid + 256 < NTEMPL) ? (v1 - mean) : 0.f;
    float q = d0 * d0 + d1 * d1;
    __syncthreads();
    #pragma unroll
    for (int o = 32; o > 0; o >>= 1) q += __shfl_down(q, o, 64);
    if (lane == 0) sred[wid] = q;
    __syncthreads();
    float var = (sred[0] + sred[1] + sred[2] + sred[3]) * (1.0f / (NTEMPL - 1));
    float stdv = sqrtf(var);
    if (stdv < EPSV) stdv = EPSV;
    float inv = 1.0f / stdv;

    float* o = tn + b * (HT * TPAD);
    for (int sIdx = tid; sIdx < HT * TPAD; sIdx += 256) {
        int i = sIdx / TPAD, j = sIdx % TPAD;
        o[sIdx] = (j < WT) ? (x[i * WT + j] - mean) * inv : 0.f;
    }
}

// ---------------- main-loop step: compile-time slot rotation ----------------
// At step i, bbf slots hold bg rows ty4+i .. ty4+i+3 (slot = row & 3).
// Template row i+1 is software-pipelined into ttf[(C+1)&1] (global, uniform
// address -> scalarizes to s_load; SGPR-resident template).
template<int C, bool LAST>
__device__ __forceinline__ void corr_step(
    int ib, int ty4, int xb,
    const float* __restrict__ tp,
    const float (*__restrict__ bg)[BP],
    float (&bbf)[4][TPAD], float (&ttf)[2][TPAD], float (&acc)[4][4])
{
    const int i = ib + C;
    if (!LAST) {
        const float4* tq = (const float4*)(tp + (i + 1) * TPAD);
        #pragma unroll
        for (int q = 0; q < 5; ++q) ((float4*)ttf[(C + 1) & 1])[q] = tq[q];
    }
    {   // load new bg row (ty4+i+3) into slot (C+3)&3 — consumed late (ry=3)
        const float4* br = (const float4*)&bg[ty4 + i + 3][xb];
        #pragma unroll
        for (int q = 0; q < 5; ++q) ((float4*)bbf[(C + 3) & 3])[q] = br[q];
    }
    const float* tc = ttf[C & 1];
    #pragma unroll
    for (int ry = 0; ry < 4; ++ry) {
        const float* rw = bbf[(C + ry) & 3];
        #pragma unroll
        for (int j = 0; j < 17; ++j) {
            const float tv = tc[j];
            #pragma unroll
            for (int k = 0; k < 4; ++k)
                acc[ry][k] = fmaf(tv, rw[j + k], acc[ry][k]);
        }
    }
}

// ---------------- kernel 2: correlation + per-tile softmax partials ----------------
// LDS = bg only (27.7 KB). launch_bounds(256,2): VGPR cap 128 (NOT (256,4):
// that capped VGPRs at 64 and spilled 3 GB to scratch — round-3 regression).
// Natural allocation ~116 VGPRs -> 4 waves/SIMD -> 4 blocks/CU.
__global__ __launch_bounds__(256, 2) void corr_kernel(
    const float* __restrict__ bgg, const float* __restrict__ tn,
    float* __restrict__ partials) {
    int blk = blockIdx.x;
    int b = blk / NTILES;
    int t = blk % NTILES;
    int ty0 = (t / NTXT) * TY;
    int tx0 = (t % NTXT) * TX;
    const float* img = bgg + (size_t)b * HI * WI;
    const float* tp  = tn + b * (HT * TPAD);

    __shared__ float bg[BR][BP];   // 27648 B
    __shared__ float redm[4], redl[4], redy[4], redx[4];

    int tid = threadIdx.x;
    int wid = tid >> 6, lane = tid & 63;

    // ---- stage bg tile (zero-filled OOB); rows/cols are 4-aligned vs 384 ----
    for (int l = tid; l < BR * (BP / 4); l += 256) {
        int r = l / (BP / 4), c = (l % (BP / 4)) * 4;
        int iy = ty0 + r, ix = tx0 + c;
        float4 v = make_float4(0.f, 0.f, 0.f, 0.f);
        if (iy < HI && ix < WI) v = *(const float4*)(img + iy * WI + ix);
        *(float4*)&bg[r][c] = v;
    }
    __syncthreads();

    // ---- main loop: 4x4 micro-tile, rolling 4-row register window ----
    int ty4 = (tid >> 5) * 4;    // 0..28
    int xb  = (tid & 31) * 4;    // 0..124
    float bbf[4][TPAD];
    float ttf[2][TPAD];
    float acc[4][4] = {};

    #pragma unroll
    for (int m = 0; m < 3; ++m) {
        const float4* br = (const float4*)&bg[ty4 + m][xb];
        #pragma unroll
        for (int q = 0; q < 5; ++q) ((float4*)bbf[m])[q] = br[q];
    }
    {
        const float4* t0 = (const float4*)tp;
        #pragma unroll
        for (int q = 0; q < 5; ++q) ((float4*)ttf[0])[q] = t0[q];
    }

    for (int ib = 0; ib < 16; ib += 4) {
        corr_step<0, false>(ib, ty4, xb, tp, bg, bbf, ttf, acc);
        corr_step<1, false>(ib, ty4, xb, tp, bg, bbf, ttf, acc);
        corr_step<2, false>(ib, ty4, xb, tp, bg, bbf, ttf, acc);
        corr_step<3, false>(ib, ty4, xb, tp, bg, bbf, ttf, acc);
    }
    corr_step<0, true>(16, ty4, xb, tp, bg, bbf, ttf, acc);

    // ---- per-thread window stats: 20-column running sums in registers ----
    // (no barrier needed: everyone only READS bg from here)
    float cs[TPAD], cs2[TPAD];
    {   // rows ty4 .. ty4+16
        const float4* r0 = (const float4*)&bg[ty4][xb];
        float tmp[TPAD];
        #pragma unroll
        for (int q = 0; q < 5; ++q) ((float4*)tmp)[q] = r0[q];
        #pragma unroll
        for (int j = 0; j < TPAD; ++j) { float v = tmp[j]; cs[j] = v; cs2[j] = v * v; }
    }
    #pragma unroll
    for (int r = 1; r < HT; ++r) {
        const float4* rr = (const float4*)&bg[ty4 + r][xb];
        float tmp[TPAD];
        #pragma unroll
        for (int q = 0; q < 5; ++q) ((float4*)tmp)[q] = rr[q];
        #pragma unroll
        for (int j = 0; j < TPAD; ++j) { float v = tmp[j]; cs[j] += v; cs2[j] = fmaf(v, v, cs2[j]); }
    }

    const float invn = 1.0f / NTEMPL;
    float corr[4][4];
    float m = -INFINITY;
    #pragma unroll
    for (int ry = 0; ry < 4; ++ry) {
        // cs/cs2 currently hold column sums over rows [ty4+ry, ty4+ry+16]
        float s1 = 0.f, s2 = 0.f;
        #pragma unroll
        for (int j = 0; j < HT; ++j) { s1 += cs[j]; s2 += cs2[j]; }
        int oy = ty0 + ty4 + ry;
        #pragma unroll
        for (int k = 0; k < 4; ++k) {
            float mu = s1 * invn;
            float var = s2 * invn - mu * mu;
            if (var < EPSV) var = EPSV;
            float cv = acc[ry][k] / sqrtf(var);
            int ox = tx0 + xb + k;
            if (oy < LH && ox < LW) m = fmaxf(m, cv);
            else cv = -INFINITY;
            corr[ry][k] = cv;
            if (k < 3) {
                s1 += cs[k + HT] - cs[k];
                s2 += cs2[k + HT] - cs2[k];
            }
        }
        if (ry < 3) {   // roll window down one row: add row ty4+ry+17, drop row ty4+ry
            float tn2[TPAD], to2[TPAD];
            const float4* rn = (const float4*)&bg[ty4 + ry + HT][xb];
            const float4* ro = (const float4*)&bg[ty4 + ry][xb];
            #pragma unroll
            for (int q = 0; q < 5; ++q) { ((float4*)tn2)[q] = rn[q]; ((float4*)to2)[q] = ro[q]; }
            #pragma unroll
            for (int j = 0; j < TPAD; ++j) {
                float vn = tn2[j], vo = to2[j];
                cs[j] += vn - vo;
                cs2[j] = fmaf(vn, vn, cs2[j]);
                cs2[j] = fmaf(-vo, vo, cs2[j]);
            }
        }
    }

    // ---- block max ----
    float mm = m;
    #pragma unroll
    for (int o = 32; o > 0; o >>= 1) mm = fmaxf(mm, __shfl_down(mm, o, 64));
    if (lane == 0) redm[wid] = mm;
    __syncthreads();
    float M = fmaxf(fmaxf(redm[0], redm[1]), fmaxf(redm[2], redm[3]));

    // ---- partial softmax sums relative to tile max ----
    float l = 0.f, sy = 0.f, sx = 0.f;
    #pragma unroll
    for (int ry = 0; ry < 4; ++ry) {
        int oy = ty0 + ty4 + ry;
        #pragma unroll
        for (int k = 0; k < 4; ++k) {
            float cv = corr[ry][k];
            float e = (cv == -INFINITY) ? 0.f : __expf((cv - M) * TEMP_INV);
            l += e;
            sy = fmaf(e, (float)oy, sy);
            sx = fmaf(e, (float)(tx0 + xb + k), sx);
        }
    }
    #pragma unroll
    for (int o = 32; o > 0; o >>= 1) {
        l  += __shfl_down(l, o, 64);
        sy += __shfl_down(sy, o, 64);
        sx += __shfl_down(sx, o, 64);
    }
    if (lane == 0) { redl[wid] = l; redy[wid] = sy; redx[wid] = sx; }
    __syncthreads();
    if (tid == 0) {
        float* p = partials + (size_t)blk * 4;
        p[0] = M;
        p[1] = redl[0] + redl[1] + redl[2] + redl[3];
        p[2] = redy[0] + redy[1] + redy[2] + redy[3];
        p[3] = redx[0] + redx[1] + redx[2] + redx[3];
    }
}

// ---------------- kernel 3: per-batch merge of tile partials ----------------
__global__ __launch_bounds__(256) void reduce_kernel(
    const float* __restrict__ partials, float* __restrict__ out) {
    int b = blockIdx.x;
    int tid = threadIdx.x;
    int wid = tid >> 6, lane = tid & 63;

    float m = -INFINITY, l = 0.f, sy = 0.f, sx = 0.f;
    if (tid < NTILES) {
        const float* p = partials + (size_t)(b * NTILES + tid) * 4;
        m = p[0]; l = p[1]; sy = p[2]; sx = p[3];
    }
    __shared__ float rm[4], rl[4], ry[4], rx[4];
    float mm = m;
    #pragma unroll
    for (int o = 32; o > 0; o >>= 1) mm = fmaxf(mm, __shfl_down(mm, o, 64));
    if (lane == 0) rm[wid] = mm;
    __syncthreads();
    float M = fmaxf(fmaxf(rm[0], rm[1]), fmaxf(rm[2], rm[3]));

    float sc = (m == -INFINITY) ? 0.f : __expf((m - M) * TEMP_INV);
    l *= sc; sy *= sc; sx *= sc;
    #pragma unroll
    for (int o = 32; o > 0; o >>= 1) {
        l  += __shfl_down(l, o, 64);
        sy += __shfl_down(sy, o, 64);
        sx += __shfl_down(sx, o, 64);
    }
    if (lane == 0) { rl[wid] = l; ry[wid] = sy; rx[wid] = sx; }
    __syncthreads();
    if (tid == 0) {
        float L  = rl[0] + rl[1] + rl[2] + rl[3];
        float SY = ry[0] + ry[1] + ry[2] + ry[3];
        float SX = rx[0] + rx[1] + rx[2] + rx[3];
        out[b * 2 + 0] = SX / L - 183.5f;
        out[b * 2 + 1] = SY / L - 183.5f;
        out[2 * NB + b] = M;
    }
}

extern "C" void kernel_launch(void* const* d_in, const int* in_sizes, int n_in,
                              void* d_out, int out_size, void* d_ws, size_t ws_size,
                              hipStream_t stream) {
    const float* piece = (const float*)d_in[0];   // [256,1,17,17]
    const float* bgg   = (const float*)d_in[1];   // [256,1,384,384]
    float* out = (float*)d_out;                   // 512 offsets + 256 max_corr

    float* tn = (float*)d_ws;                     // 256 * 340 floats
    float* partials = tn + NB * HT * TPAD;        // 256*36*4 floats

    tmpl_norm_kernel<<<NB, 256, 0, stream>>>(piece, tn);
    corr_kernel<<<NB * NTILES, 256, 0, stream>>>(bgg, tn, partials);
    reduce_kernel<<<NB, 256, 0, stream>>>(partials, out);
}

// Round 5
// 564.657 us; speedup vs baseline: 1.8037x; 1.0034x over previous
//
#include <hip/hip_runtime.h>
#include <math.h>

#define NB 256       // batch
#define HT 17
#define WT 17
#define HI 384
#define WI 384
#define LH 368
#define LW 368
#define NTEMPL 289   // HT*WT
#define TPAD 20      // padded template row width (float4-friendly)
#define TY 32        // output tile rows per block
#define TX 128       // output tile cols per block
#define NTXT 3       // x tiles (3*128 = 384)
#define NTYT 12      // y tiles (12*32 = 384)
#define NTILES 36    // tiles per batch
#define BR 48        // bg tile rows (TY + 16)
#define BP 144       // bg pitch = TX + 16 (multiple of 4)
#define TEMP_INV 25.0f
#define EPSV 1e-6f

// ---------------- kernel 1: per-batch template normalization ----------------
__global__ __launch_bounds__(256) void tmpl_norm_kernel(
    const float* __restrict__ piece, float* __restrict__ tn) {
    int b = blockIdx.x;
    const float* x = piece + b * NTEMPL;
    int tid = threadIdx.x;
    int wid = tid >> 6, lane = tid & 63;

    float v0 = (tid < NTEMPL) ? x[tid] : 0.f;
    float v1 = (tid + 256 < NTEMPL) ? x[tid + 256] : 0.f;

    __shared__ float sred[4];
    float s = v0 + v1;
    #pragma unroll
    for (int o = 32; o > 0; o >>= 1) s += __shfl_down(s, o, 64);
    if (lane == 0) sred[wid] = s;
    __syncthreads();
    float mean = (sred[0] + sred[1] + sred[2] + sred[3]) * (1.0f / NTEMPL);

    float d0 = (tid < NTEMPL) ? (v0 - mean) : 0.f;
    float d1 = (tid + 256 < NTEMPL) ? (v1 - mean) : 0.f;
    float q = d0 * d0 + d1 * d1;
    __syncthreads();
    #pragma unroll
    for (int o = 32; o > 0; o >>= 1) q += __shfl_down(q, o, 64);
    if (lane == 0) sred[wid] = q;
    __syncthreads();
    float var = (sred[0] + sred[1] + sred[2] + sred[3]) * (1.0f / (NTEMPL - 1));
    float stdv = sqrtf(var);
    if (stdv < EPSV) stdv = EPSV;
    float inv = 1.0f / stdv;

    float* o = tn + b * (HT * TPAD);
    for (int sIdx = tid; sIdx < HT * TPAD; sIdx += 256) {
        int i = sIdx / TPAD, j = sIdx % TPAD;
        o[sIdx] = (j < WT) ? (x[i * WT + j] - mean) * inv : 0.f;
    }
}

// ---------------- main-loop step: compile-time slot rotation ----------------
// At step i, bbf slots hold bg rows ty4+i .. ty4+i+3 (slot = row & 3).
// Template row i+1 is software-pipelined into ttf[(C+1)&1] (global, uniform
// address -> scalarizes to s_load; SGPR-resident template).
template<int C, bool LAST>
__device__ __forceinline__ void corr_step(
    int ib, int ty4, int xb,
    const float* __restrict__ tp,
    const float (*__restrict__ bg)[BP],
    float (&bbf)[4][TPAD], float (&ttf)[2][TPAD], float (&acc)[4][4])
{
    const int i = ib + C;
    if (!LAST) {
        const float4* tq = (const float4*)(tp + (i + 1) * TPAD);
        #pragma unroll
        for (int q = 0; q < 5; ++q) ((float4*)ttf[(C + 1) & 1])[q] = tq[q];
    }
    {   // load new bg row (ty4+i+3) into slot (C+3)&3 — consumed late (ry=3)
        const float4* br = (const float4*)&bg[ty4 + i + 3][xb];
        #pragma unroll
        for (int q = 0; q < 5; ++q) ((float4*)bbf[(C + 3) & 3])[q] = br[q];
    }
    const float* tc = ttf[C & 1];
    #pragma unroll
    for (int ry = 0; ry < 4; ++ry) {
        const float* rw = bbf[(C + ry) & 3];
        #pragma unroll
        for (int j = 0; j < 17; ++j) {
            const float tv = tc[j];
            #pragma unroll
            for (int k = 0; k < 4; ++k)
                acc[ry][k] = fmaf(tv, rw[j + k], acc[ry][k]);
        }
    }
}

// ---------------- kernel 2: correlation + per-tile softmax partials ----------------
// LDS = bg only (27.7 KB). NO second launch_bounds arg: on this toolchain the
// waves-per-eu attribute acts as a HARD runtime occupancy cap (r2/r4: arg=2
// -> pinned at 22.6% despite VGPR=116 allowing 4 waves/EU; r3: arg=4 -> VGPR
// forced to 64 -> 3 GB scratch spills). Natural allocation ~116 VGPR -> 4
// waves/SIMD hardware-allowed.
__global__ __launch_bounds__(256) void corr_kernel(
    const float* __restrict__ bgg, const float* __restrict__ tn,
    float* __restrict__ partials) {
    int blk = blockIdx.x;
    int b = blk / NTILES;
    int t = blk % NTILES;
    int ty0 = (t / NTXT) * TY;
    int tx0 = (t % NTXT) * TX;
    const float* img = bgg + (size_t)b * HI * WI;
    const float* tp  = tn + b * (HT * TPAD);

    __shared__ float bg[BR][BP];   // 27648 B
    __shared__ float redm[4], redl[4], redy[4], redx[4];

    int tid = threadIdx.x;
    int wid = tid >> 6, lane = tid & 63;

    // ---- stage bg tile (zero-filled OOB); rows/cols are 4-aligned vs 384 ----
    for (int l = tid; l < BR * (BP / 4); l += 256) {
        int r = l / (BP / 4), c = (l % (BP / 4)) * 4;
        int iy = ty0 + r, ix = tx0 + c;
        float4 v = make_float4(0.f, 0.f, 0.f, 0.f);
        if (iy < HI && ix < WI) v = *(const float4*)(img + iy * WI + ix);
        *(float4*)&bg[r][c] = v;
    }
    __syncthreads();

    // ---- main loop: 4x4 micro-tile, rolling 4-row register window ----
    int ty4 = (tid >> 5) * 4;    // 0..28
    int xb  = (tid & 31) * 4;    // 0..124
    float bbf[4][TPAD];
    float ttf[2][TPAD];
    float acc[4][4] = {};

    #pragma unroll
    for (int m = 0; m < 3; ++m) {
        const float4* br = (const float4*)&bg[ty4 + m][xb];
        #pragma unroll
        for (int q = 0; q < 5; ++q) ((float4*)bbf[m])[q] = br[q];
    }
    {
        const float4* t0 = (const float4*)tp;
        #pragma unroll
        for (int q = 0; q < 5; ++q) ((float4*)ttf[0])[q] = t0[q];
    }

    for (int ib = 0; ib < 16; ib += 4) {
        corr_step<0, false>(ib, ty4, xb, tp, bg, bbf, ttf, acc);
        corr_step<1, false>(ib, ty4, xb, tp, bg, bbf, ttf, acc);
        corr_step<2, false>(ib, ty4, xb, tp, bg, bbf, ttf, acc);
        corr_step<3, false>(ib, ty4, xb, tp, bg, bbf, ttf, acc);
    }
    corr_step<0, true>(16, ty4, xb, tp, bg, bbf, ttf, acc);

    // ---- per-thread window stats: 20-column running sums in registers ----
    // (no barrier needed: everyone only READS bg from here)
    float cs[TPAD], cs2[TPAD];
    {   // rows ty4 .. ty4+16
        const float4* r0 = (const float4*)&bg[ty4][xb];
        float tmp[TPAD];
        #pragma unroll
        for (int q = 0; q < 5; ++q) ((float4*)tmp)[q] = r0[q];
        #pragma unroll
        for (int j = 0; j < TPAD; ++j) { float v = tmp[j]; cs[j] = v; cs2[j] = v * v; }
    }
    #pragma unroll
    for (int r = 1; r < HT; ++r) {
        const float4* rr = (const float4*)&bg[ty4 + r][xb];
        float tmp[TPAD];
        #pragma unroll
        for (int q = 0; q < 5; ++q) ((float4*)tmp)[q] = rr[q];
        #pragma unroll
        for (int j = 0; j < TPAD; ++j) { float v = tmp[j]; cs[j] += v; cs2[j] = fmaf(v, v, cs2[j]); }
    }

    const float invn = 1.0f / NTEMPL;
    float corr[4][4];
    float m = -INFINITY;
    #pragma unroll
    for (int ry = 0; ry < 4; ++ry) {
        // cs/cs2 currently hold column sums over rows [ty4+ry, ty4+ry+16]
        float s1 = 0.f, s2 = 0.f;
        #pragma unroll
        for (int j = 0; j < HT; ++j) { s1 += cs[j]; s2 += cs2[j]; }
        int oy = ty0 + ty4 + ry;
        #pragma unroll
        for (int k = 0; k < 4; ++k) {
            float mu = s1 * invn;
            float var = s2 * invn - mu * mu;
            if (var < EPSV) var = EPSV;
            float cv = acc[ry][k] / sqrtf(var);
            int ox = tx0 + xb + k;
            if (oy < LH && ox < LW) m = fmaxf(m, cv);
            else cv = -INFINITY;
            corr[ry][k] = cv;
            if (k < 3) {
                s1 += cs[k + HT] - cs[k];
                s2 += cs2[k + HT] - cs2[k];
            }
        }
        if (ry < 3) {   // roll window down one row: add row ty4+ry+17, drop row ty4+ry
            float tn2[TPAD], to2[TPAD];
            const float4* rn = (const float4*)&bg[ty4 + ry + HT][xb];
            const float4* ro = (const float4*)&bg[ty4 + ry][xb];
            #pragma unroll
            for (int q = 0; q < 5; ++q) { ((float4*)tn2)[q] = rn[q]; ((float4*)to2)[q] = ro[q]; }
            #pragma unroll
            for (int j = 0; j < TPAD; ++j) {
                float vn = tn2[j], vo = to2[j];
                cs[j] += vn - vo;
                cs2[j] = fmaf(vn, vn, cs2[j]);
                cs2[j] = fmaf(-vo, vo, cs2[j]);
            }
        }
    }

    // ---- block max ----
    float mm = m;
    #pragma unroll
    for (int o = 32; o > 0; o >>= 1) mm = fmaxf(mm, __shfl_down(mm, o, 64));
    if (lane == 0) redm[wid] = mm;
    __syncthreads();
    float M = fmaxf(fmaxf(redm[0], redm[1]), fmaxf(redm[2], redm[3]));

    // ---- partial softmax sums relative to tile max ----
    float l = 0.f, sy = 0.f, sx = 0.f;
    #pragma unroll
    for (int ry = 0; ry < 4; ++ry) {
        int oy = ty0 + ty4 + ry;
        #pragma unroll
        for (int k = 0; k < 4; ++k) {
            float cv = corr[ry][k];
            float e = (cv == -INFINITY) ? 0.f : __expf((cv - M) * TEMP_INV);
            l += e;
            sy = fmaf(e, (float)oy, sy);
            sx = fmaf(e, (float)(tx0 + xb + k), sx);
        }
    }
    #pragma unroll
    for (int o = 32; o > 0; o >>= 1) {
        l  += __shfl_down(l, o, 64);
        sy += __shfl_down(sy, o, 64);
        sx += __shfl_down(sx, o, 64);
    }
    if (lane == 0) { redl[wid] = l; redy[wid] = sy; redx[wid] = sx; }
    __syncthreads();
    if (tid == 0) {
        float* p = partials + (size_t)blk * 4;
        p[0] = M;
        p[1] = redl[0] + redl[1] + redl[2] + redl[3];
        p[2] = redy[0] + redy[1] + redy[2] + redy[3];
        p[3] = redx[0] + redx[1] + redx[2] + redx[3];
    }
}

// ---------------- kernel 3: per-batch merge of tile partials ----------------
__global__ __launch_bounds__(256) void reduce_kernel(
    const float* __restrict__ partials, float* __restrict__ out) {
    int b = blockIdx.x;
    int tid = threadIdx.x;
    int wid = tid >> 6, lane = tid & 63;

    float m = -INFINITY, l = 0.f, sy = 0.f, sx = 0.f;
    if (tid < NTILES) {
        const float* p = partials + (size_t)(b * NTILES + tid) * 4;
        m = p[0]; l = p[1]; sy = p[2]; sx = p[3];
    }
    __shared__ float rm[4], rl[4], ry[4], rx[4];
    float mm = m;
    #pragma unroll
    for (int o = 32; o > 0; o >>= 1) mm = fmaxf(mm, __shfl_down(mm, o, 64));
    if (lane == 0) rm[wid] = mm;
    __syncthreads();
    float M = fmaxf(fmaxf(rm[0], rm[1]), fmaxf(rm[2], rm[3]));

    float sc = (m == -INFINITY) ? 0.f : __expf((m - M) * TEMP_INV);
    l *= sc; sy *= sc; sx *= sc;
    #pragma unroll
    for (int o = 32; o > 0; o >>= 1) {
        l  += __shfl_down(l, o, 64);
        sy += __shfl_down(sy, o, 64);
        sx += __shfl_down(sx, o, 64);
    }
    if (lane == 0) { rl[wid] = l; ry[wid] = sy; rx[wid] = sx; }
    __syncthreads();
    if (tid == 0) {
        float L  = rl[0] + rl[1] + rl[2] + rl[3];
        float SY = ry[0] + ry[1] + ry[2] + ry[3];
        float SX = rx[0] + rx[1] + rx[2] + rx[3];
        out[b * 2 + 0] = SX / L - 183.5f;
        out[b * 2 + 1] = SY / L - 183.5f;
        out[2 * NB + b] = M;
    }
}

extern "C" void kernel_launch(void* const* d_in, const int* in_sizes, int n_in,
                              void* d_out, int out_size, void* d_ws, size_t ws_size,
                              hipStream_t stream) {
    const float* piece = (const float*)d_in[0];   // [256,1,17,17]
    const float* bgg   = (const float*)d_in[1];   // [256,1,384,384]
    float* out = (float*)d_out;                   // 512 offsets + 256 max_corr

    float* tn = (float*)d_ws;                     // 256 * 340 floats
    float* partials = tn + NB * HT * TPAD;        // 256*36*4 floats

    tmpl_norm_kernel<<<NB, 256, 0, stream>>>(piece, tn);
    corr_kernel<<<NB * NTILES, 256, 0, stream>>>(bgg, tn, partials);
    reduce_kernel<<<NB, 256, 0, stream>>>(partials, out);
}

// Round 6
// 531.632 us; speedup vs baseline: 1.9157x; 1.0621x over previous
//
#include <hip/hip_runtime.h>
#include <math.h>

#define NB 256       // batch
#define HT 17
#define WT 17
#define HI 384
#define WI 384
#define LH 368
#define LW 368
#define NTEMPL 289   // HT*WT
#define TPAD 20      // padded template row width (float4-friendly)
#define TY 32        // output tile rows per block
#define TX 64        // output tile cols per block
#define NTXT 6       // x tiles (6*64 = 384)
#define NTYT 12      // y tiles (12*32 = 384)
#define NTILES 72    // tiles per batch
#define BR 48        // bg tile rows (TY + 16)
#define BP 84        // bg/c1/c2 pitch: 64+16 used, 84 = 4-mult, 84%32=20 -> bank rotation
#define TEMP_INV 25.0f
#define EPSV 1e-6f

// ---------------- kernel 1: per-batch template normalization ----------------
__global__ __launch_bounds__(256) void tmpl_norm_kernel(
    const float* __restrict__ piece, float* __restrict__ tn) {
    int b = blockIdx.x;
    const float* x = piece + b * NTEMPL;
    int tid = threadIdx.x;
    int wid = tid >> 6, lane = tid & 63;

    float v0 = (tid < NTEMPL) ? x[tid] : 0.f;
    float v1 = (tid + 256 < NTEMPL) ? x[tid + 256] : 0.f;

    __shared__ float sred[4];
    float s = v0 + v1;
    #pragma unroll
    for (int o = 32; o > 0; o >>= 1) s += __shfl_down(s, o, 64);
    if (lane == 0) sred[wid] = s;
    __syncthreads();
    float mean = (sred[0] + sred[1] + sred[2] + sred[3]) * (1.0f / NTEMPL);

    float d0 = (tid < NTEMPL) ? (v0 - mean) : 0.f;
    float d1 = (tid + 256 < NTEMPL) ? (v1 - mean) : 0.f;
    float q = d0 * d0 + d1 * d1;
    __syncthreads();
    #pragma unroll
    for (int o = 32; o > 0; o >>= 1) q += __shfl_down(q, o, 64);
    if (lane == 0) sred[wid] = q;
    __syncthreads();
    float var = (sred[0] + sred[1] + sred[2] + sred[3]) * (1.0f / (NTEMPL - 1));
    float stdv = sqrtf(var);
    if (stdv < EPSV) stdv = EPSV;
    float inv = 1.0f / stdv;

    float* o = tn + b * (HT * TPAD);
    for (int sIdx = tid; sIdx < HT * TPAD; sIdx += 256) {
        int i = sIdx / TPAD, j = sIdx % TPAD;
        o[sIdx] = (j < WT) ? (x[i * WT + j] - mean) * inv : 0.f;
    }
}

// ---------------- main-loop step, 2-row window, compile-time parity ----------------
// Before step i: bbf[i&1] = bg row tr2+i, bbf[(i+1)&1] = bg row tr2+i+1,
// ttf[i&1] = template row i. Order inside the step (dataflow-enforced):
//   FMA out0 (slot P) -> prefetch row tr2+i+2 into slot P -> FMA out1 (slot P^1).
template<int P, bool LAST>
__device__ __forceinline__ void corr_step(
    int i, int tr2, int xb,
    const float* __restrict__ tp,
    const float (*__restrict__ bg)[BP],
    float (&bbf)[2][TPAD], float (&ttf)[2][TPAD], float (&acc)[2][4])
{
    if (!LAST) {   // template row i+1 -> other ttf slot (uniform addr -> s_load/SGPR)
        const float4* tq = (const float4*)(tp + (i + 1) * TPAD);
        #pragma unroll
        for (int q = 0; q < 5; ++q) ((float4*)ttf[P ^ 1])[q] = tq[q];
    }
    const float* tc = ttf[P];
    #pragma unroll
    for (int j = 0; j < 17; ++j) {         // out row 0: bg row tr2+i (slot P)
        float tv = tc[j];
        #pragma unroll
        for (int k = 0; k < 4; ++k) acc[0][k] = fmaf(tv, bbf[P][j + k], acc[0][k]);
    }
    if (!LAST) {   // prefetch bg row tr2+i+2 into slot P (out0 done with it)
        const float4* br = (const float4*)&bg[tr2 + i + 2][xb];
        #pragma unroll
        for (int q = 0; q < 5; ++q) ((float4*)bbf[P])[q] = br[q];
    }
    #pragma unroll
    for (int j = 0; j < 17; ++j) {         // out row 1: bg row tr2+i+1 (slot P^1)
        float tv = tc[j];
        #pragma unroll
        for (int k = 0; k < 4; ++k) acc[1][k] = fmaf(tv, bbf[P ^ 1][j + k], acc[1][k]);
    }
}

// ---------------- kernel 2: correlation + per-tile softmax partials ----------------
// Occupancy law (r1-r5 measured): waves/SIMD = floor(256/VGPR). 2x4 micro-tile
// live set ~58 VGPR; (256,4) pins cap at 64 -> 4 waves/SIMD. LDS 37.9 KB -> 4
// blocks/CU. (r3 lesson: cap below live set => GB-scale scratch; check
// WRITE_SIZE stays ~KB.)
__global__ __launch_bounds__(256, 4) void corr_kernel(
    const float* __restrict__ bgg, const float* __restrict__ tn,
    float* __restrict__ partials) {
    int blk = blockIdx.x;
    int b = blk / NTILES;
    int t = blk % NTILES;
    int ty0 = (t / NTXT) * TY;
    int tx0 = (t % NTXT) * TX;
    const float* img = bgg + (size_t)b * HI * WI;
    const float* tp  = tn + b * (HT * TPAD);

    __shared__ float bg[BR][BP];   // 16128 B
    __shared__ float c1[TY][BP];   // 10752 B (17-row column sums)
    __shared__ float c2[TY][BP];   // 10752 B (17-row column sums of squares)
    __shared__ float redm[4], redl[4], redy[4], redx[4];

    int tid = threadIdx.x;
    int wid = tid >> 6, lane = tid & 63;

    // ---- stage bg tile (zero-filled OOB); 48 x 21 float4 ----
    for (int l = tid; l < BR * (BP / 4); l += 256) {
        int r = l / (BP / 4), c = (l % (BP / 4)) * 4;
        int iy = ty0 + r, ix = tx0 + c;
        float4 v = make_float4(0.f, 0.f, 0.f, 0.f);
        if (iy < HI && ix < WI) v = *(const float4*)(img + iy * WI + ix);
        *(float4*)&bg[r][c] = v;
    }
    __syncthreads();

    // ---- cooperative 17-row column sums, incremental chains (160 tasks) ----
    if (tid < 160) {
        int cc = tid % 80, r0 = (tid / 80) * 16;
        float s = 0.f, s2 = 0.f;
        #pragma unroll
        for (int i2 = 0; i2 < HT; ++i2) { float v = bg[r0 + i2][cc]; s += v; s2 = fmaf(v, v, s2); }
        c1[r0][cc] = s; c2[r0][cc] = s2;
        for (int r = r0 + 1; r < r0 + 16; ++r) {
            float vn = bg[r + 16][cc], vo = bg[r - 1][cc];
            s += vn - vo; s2 += vn * vn - vo * vo;
            c1[r][cc] = s; c2[r][cc] = s2;
        }
    }
    __syncthreads();   // c1/c2 ready before epilogue; bg stable for main loop

    // ---- main loop: 2x4 micro-tile, rolling 2-row register window ----
    int tr2 = (tid >> 4) * 2;    // 0..30 (output row pair)
    int xb  = (tid & 15) * 4;    // 0..60
    float bbf[2][TPAD];
    float ttf[2][TPAD];
    float acc[2][4] = {};

    #pragma unroll
    for (int m = 0; m < 2; ++m) {
        const float4* br = (const float4*)&bg[tr2 + m][xb];
        #pragma unroll
        for (int q = 0; q < 5; ++q) ((float4*)bbf[m])[q] = br[q];
    }
    {
        const float4* t0 = (const float4*)tp;
        #pragma unroll
        for (int q = 0; q < 5; ++q) ((float4*)ttf[0])[q] = t0[q];
    }

    for (int i = 0; i < 16; i += 2) {
        corr_step<0, false>(i,     tr2, xb, tp, bg, bbf, ttf, acc);
        corr_step<1, false>(i + 1, tr2, xb, tp, bg, bbf, ttf, acc);
    }
    corr_step<0, true>(16, tr2, xb, tp, bg, bbf, ttf, acc);

    // ---- window stats from c1/c2 (float4 reads) + sliding update ----
    const float invn = 1.0f / NTEMPL;
    float corr[2][4];
    float m = -INFINITY;
    #pragma unroll
    for (int e = 0; e < 2; ++e) {
        float cc1f[TPAD], cc2f[TPAD];
        const float4* a1 = (const float4*)&c1[tr2 + e][xb];
        const float4* a2 = (const float4*)&c2[tr2 + e][xb];
        #pragma unroll
        for (int q = 0; q < 5; ++q) { ((float4*)cc1f)[q] = a1[q]; ((float4*)cc2f)[q] = a2[q]; }
        float s1 = 0.f, s2 = 0.f;
        #pragma unroll
        for (int j = 0; j < HT; ++j) { s1 += cc1f[j]; s2 += cc2f[j]; }
        int oy = ty0 + tr2 + e;
        #pragma unroll
        for (int k = 0; k < 4; ++k) {
            float mu = s1 * invn;
            float var = s2 * invn - mu * mu;
            if (var < EPSV) var = EPSV;
            float cv = acc[e][k] / sqrtf(var);
            int ox = tx0 + xb + k;
            if (oy < LH && ox < LW) m = fmaxf(m, cv);
            else cv = -INFINITY;
            corr[e][k] = cv;
            if (k < 3) {
                s1 += cc1f[k + HT] - cc1f[k];
                s2 += cc2f[k + HT] - cc2f[k];
            }
        }
    }

    // ---- block max ----
    float mm = m;
    #pragma unroll
    for (int o = 32; o > 0; o >>= 1) mm = fmaxf(mm, __shfl_down(mm, o, 64));
    if (lane == 0) redm[wid] = mm;
    __syncthreads();
    float M = fmaxf(fmaxf(redm[0], redm[1]), fmaxf(redm[2], redm[3]));

    // ---- partial softmax sums relative to tile max ----
    float l = 0.f, sy = 0.f, sx = 0.f;
    #pragma unroll
    for (int e = 0; e < 2; ++e) {
        int oy = ty0 + tr2 + e;
        #pragma unroll
        for (int k = 0; k < 4; ++k) {
            float cv = corr[e][k];
            float ev = (cv == -INFINITY) ? 0.f : __expf((cv - M) * TEMP_INV);
            l += ev;
            sy = fmaf(ev, (float)oy, sy);
            sx = fmaf(ev, (float)(tx0 + xb + k), sx);
        }
    }
    #pragma unroll
    for (int o = 32; o > 0; o >>= 1) {
        l  += __shfl_down(l, o, 64);
        sy += __shfl_down(sy, o, 64);
        sx += __shfl_down(sx, o, 64);
    }
    if (lane == 0) { redl[wid] = l; redy[wid] = sy; redx[wid] = sx; }
    __syncthreads();
    if (tid == 0) {
        float* p = partials + (size_t)blk * 4;
        p[0] = M;
        p[1] = redl[0] + redl[1] + redl[2] + redl[3];
        p[2] = redy[0] + redy[1] + redy[2] + redy[3];
        p[3] = redx[0] + redx[1] + redx[2] + redx[3];
    }
}

// ---------------- kernel 3: per-batch merge of tile partials ----------------
__global__ __launch_bounds__(256) void reduce_kernel(
    const float* __restrict__ partials, float* __restrict__ out) {
    int b = blockIdx.x;
    int tid = threadIdx.x;
    int wid = tid >> 6, lane = tid & 63;

    float m = -INFINITY, l = 0.f, sy = 0.f, sx = 0.f;
    if (tid < NTILES) {
        const float* p = partials + (size_t)(b * NTILES + tid) * 4;
        m = p[0]; l = p[1]; sy = p[2]; sx = p[3];
    }
    __shared__ float rm[4], rl[4], ry[4], rx[4];
    float mm = m;
    #pragma unroll
    for (int o = 32; o > 0; o >>= 1) mm = fmaxf(mm, __shfl_down(mm, o, 64));
    if (lane == 0) rm[wid] = mm;
    __syncthreads();
    float M = fmaxf(fmaxf(rm[0], rm[1]), fmaxf(rm[2], rm[3]));

    float sc = (m == -INFINITY) ? 0.f : __expf((m - M) * TEMP_INV);
    l *= sc; sy *= sc; sx *= sc;
    #pragma unroll
    for (int o = 32; o > 0; o >>= 1) {
        l  += __shfl_down(l, o, 64);
        sy += __shfl_down(sy, o, 64);
        sx += __shfl_down(sx, o, 64);
    }
    if (lane == 0) { rl[wid] = l; ry[wid] = sy; rx[wid] = sx; }
    __syncthreads();
    if (tid == 0) {
        float L  = rl[0] + rl[1] + rl[2] + rl[3];
        float SY = ry[0] + ry[1] + ry[2] + ry[3];
        float SX = rx[0] + rx[1] + rx[2] + rx[3];
        out[b * 2 + 0] = SX / L - 183.5f;
        out[b * 2 + 1] = SY / L - 183.5f;
        out[2 * NB + b] = M;
    }
}

extern "C" void kernel_launch(void* const* d_in, const int* in_sizes, int n_in,
                              void* d_out, int out_size, void* d_ws, size_t ws_size,
                              hipStream_t stream) {
    const float* piece = (const float*)d_in[0];   // [256,1,17,17]
    const float* bgg   = (const float*)d_in[1];   // [256,1,384,384]
    float* out = (float*)d_out;                   // 512 offsets + 256 max_corr

    float* tn = (float*)d_ws;                     // 256 * 340 floats
    float* partials = tn + NB * HT * TPAD;        // 256*72*4 floats

    tmpl_norm_kernel<<<NB, 256, 0, stream>>>(piece, tn);
    corr_kernel<<<NB * NTILES, 256, 0, stream>>>(bgg, tn, partials);
    reduce_kernel<<<NB, 256, 0, stream>>>(partials, out);
}